// Round 7
// baseline (774.103 us; speedup 1.0000x reference)
//
#include <hip/hip_runtime.h>

// CTRNN: T=512, B=256, I=64, H=256.
//   pre = x_t @ W_in^T + b_in + h @ W_hh^T + b_hh + noise_t
//   h   = max(0.8*h + 0.2*pre, 0)
//
// R6 post-mortem: lgkm-only barriers did NOT help rec (374->393us) -> the
// barrier vmcnt-drain theory is dead. prex is LDS-broadcast-read bound
// (16 waves x 2048 ds_read_b128 ~ 393K cyc LDS pipe vs 440K total).
// R7:
//  - ctrnn_prex4: NO LDS, NO barriers. x[pair, k] is wave-uniform -> load
//    directly per wave (HW broadcasts identical lane addresses; uniform
//    loads can become s_load). Each thread: full k=64 dot for one col,
//    w[64] in regs at the PROVEN (512,2)/128-VGPR shape. floor ~27us.
//  - ctrnn_rec3: the one-barrier structure (wave-private h, spread reduce;
//    harness-verified correct in R1/R3, never measured spill-free) with a
//    new VGPR lever: pad pbuf so static LDS ~100 KB > 80 KB -> only ONE
//    1024-thr block fits per CU -> allocator's occupancy target drops to
//    4 waves/EU -> 128-VGPR budget -> 64 weights + ~36 misc fit, no spill.
//    (waves_per_eu(4,4) alone failed in R4; LDS is an occupancy input the
//    allocator cannot ignore.) Falsifier: VGPR_Count=64 again => revert.

#define T_STEPS 512
#define BATCH   256
#define INSZ    64
#define HID     256
#define ALPHA_F 0.2f
#define OMA_F   0.8f

// ---------------------------------------------------------------------------
// Kernel 1: prex = x @ W_in^T + b_in + b_hh + noise(t)   [biases folded]
// 512 blocks (= t) x 512 threads, 2 blocks/CU. Wave wv: cols
// [(wv&3)*64, +64), batch-parity group wg=wv>>2 handles pairs p=wg,wg+2,...
// x[p,0:64] is wave-uniform -> broadcast loads, no LDS, no barriers.
// ---------------------------------------------------------------------------
__global__ __launch_bounds__(512, 2)
void ctrnn_prex4(const float* __restrict__ x,      // [T, B, I]
                 const float* __restrict__ noise,  // [T, H]
                 const float* __restrict__ W_in,   // [H, I]
                 const float* __restrict__ b_in,   // [H]
                 const float* __restrict__ b_hh,   // [H]
                 float* __restrict__ prex)         // [T, B, H] (ws)
{
    const int tid  = threadIdx.x;
    const int lane = tid & 63;
    const int wv   = tid >> 6;              // 0..7
    const int col  = (wv & 3) * 64 + lane;  // 0..255
    const int wg   = wv >> 2;               // 0..1 batch-parity group
    const int bb   = blockIdx.x;            // == t

    // W_in row in 64 VGPRs (proven no-spill shape: 512 thr, 128-VGPR budget)
    float w[INSZ];
#pragma unroll
    for (int k = 0; k < INSZ; k += 4) {
        float4 v = *reinterpret_cast<const float4*>(&W_in[col * INSZ + k]);
        w[k] = v.x; w[k+1] = v.y; w[k+2] = v.z; w[k+3] = v.w;
    }
    const float bias = b_in[col] + b_hh[col] + noise[bb * HID + col];

    const float* xrow = &x[(size_t)bb * BATCH * INSZ + (size_t)wg * INSZ];
    float*       orow = &prex[((size_t)bb * BATCH + wg) * HID + col];

#pragma unroll 2
    for (int p = 0; p < 128; ++p) {         // pair = wg + 2*p
        const float* xp = xrow + (size_t)p * 2 * INSZ;  // wave-uniform addr
        float a0 = 0.f, a1 = 0.f, a2 = 0.f, a3 = 0.f;
#pragma unroll
        for (int k = 0; k < INSZ; k += 4) { // FULL unroll: w[] const-indexed
            float4 xv = *reinterpret_cast<const float4*>(&xp[k]);
            a0 = fmaf(w[k],     xv.x, a0);
            a1 = fmaf(w[k + 1], xv.y, a1);
            a2 = fmaf(w[k + 2], xv.z, a2);
            a3 = fmaf(w[k + 3], xv.w, a3);
        }
        orow[(size_t)p * 2 * HID] = (a0 + a1) + (a2 + a3) + bias; // coalesced
    }
}

// ---------------------------------------------------------------------------
// Kernel 2: recurrence, ONE barrier per step. 256 blocks x 1024 threads.
// Wave g owns h rows [16g,16g+16) AND k-chunk [16g,16g+16) -> h wave-private
// (hbuf write->read same wave, program-ordered). Spread reduce: lane l sums
// waves {q,q+4,q+8,q+12} (q=l>>4) then shfl_xor 16/32. pbuf double-buffered
// (WAR separated by 2 barriers). pbuf PADDED 3x -> LDS ~100 KB: only one
// block/CU can fit -> allocator budget 128 VGPR -> w[4][16] stays in regs.
// ---------------------------------------------------------------------------
__global__ __launch_bounds__(1024)
__attribute__((amdgpu_waves_per_eu(4, 4)))
void ctrnn_rec3(const float* __restrict__ hidden,  // [B, H]
                const float* __restrict__ prex,    // [T, B, H] (ws, biases in)
                const float* __restrict__ W_hh,    // [H, H]
                float* __restrict__ out)           // [T,B,H] ++ [B,H]
{
    const int tid  = threadIdx.x;
    const int lane = tid & 63;
    const int g    = tid >> 6;           // wave 0..15: rows & k-chunk [16g,16g+16)
    const int b    = blockIdx.x;

    __shared__ __align__(16) float hbuf[HID];
    // 3x padded: only [0, 16*264) of each buffer used; allocation 2*12672*4B
    // = 101376 B (+hbuf 1KB) > 80 KB -> occupancy forced to 1 block/CU.
    __shared__ __align__(16) float pbuf[2][16 * 264 * 3];

    // W_hh: 4 rows x 16 k = 64 floats, FULLY const-indexed.
    float w[4][16];
#pragma unroll
    for (int m = 0; m < 4; ++m) {
        const float* wr = &W_hh[(lane + 64 * m) * HID + 16 * g];
#pragma unroll
        for (int c = 0; c < 4; ++c) {
            float4 v = *reinterpret_cast<const float4*>(&wr[4 * c]);
            w[m][4*c]   = v.x; w[m][4*c+1] = v.y;
            w[m][4*c+2] = v.z; w[m][4*c+3] = v.w;
        }
    }

    const int rrow = 16 * g + (lane & 15);   // row this lane reduces/updates
    float hj = hidden[b * HID + rrow];

    // prex pointer chain, 2-deep prefetch (4 q-lanes share each address ->
    // coalesced into one request).
    const float* pp = &prex[(size_t)b * HID + rrow];
    float pcur = pp[0];                       // t = 0
    float pn1  = pp[BATCH * HID];             // t = 1
    pp += 2 * (size_t)BATCH * HID;
    float* op = &out[(size_t)b * HID + rrow];

    if (lane < 16) hbuf[rrow] = hj;           // wave-private h init
    __syncthreads();

    const int redoff = ((g >> 2) << 6) + ((g & 3) << 4) + (lane & 15);
    const int q = lane >> 4;

#pragma unroll 1
    for (int t = 0; t < T_STEPS; ++t) {
        const int cur = t & 1;

        // prefetch prex(t+2)
        float pn2 = 0.f;
        if (t + 2 < T_STEPS) pn2 = pp[0];
        pp += (size_t)BATCH * HID;

        // ---- FMA phase: h chunk is wave-private (written last step) ----
        const float4 h0 = *reinterpret_cast<const float4*>(&hbuf[16 * g]);
        const float4 h1 = *reinterpret_cast<const float4*>(&hbuf[16 * g + 4]);
        const float4 h2 = *reinterpret_cast<const float4*>(&hbuf[16 * g + 8]);
        const float4 h3 = *reinterpret_cast<const float4*>(&hbuf[16 * g + 12]);

        float accs[4];
#pragma unroll
        for (int m = 0; m < 4; ++m) {         // FULL unroll: const indices only
            float a  = w[m][0] * h0.x;
            float bq = w[m][1] * h0.y;
            a  = fmaf(w[m][2],  h0.z, a);  bq = fmaf(w[m][3],  h0.w, bq);
            a  = fmaf(w[m][4],  h1.x, a);  bq = fmaf(w[m][5],  h1.y, bq);
            a  = fmaf(w[m][6],  h1.z, a);  bq = fmaf(w[m][7],  h1.w, bq);
            a  = fmaf(w[m][8],  h2.x, a);  bq = fmaf(w[m][9],  h2.y, bq);
            a  = fmaf(w[m][10], h2.z, a);  bq = fmaf(w[m][11], h2.w, bq);
            a  = fmaf(w[m][12], h3.x, a);  bq = fmaf(w[m][13], h3.y, bq);
            a  = fmaf(w[m][14], h3.z, a);  bq = fmaf(w[m][15], h3.w, bq);
            accs[m] = a + bq;
        }

        // Partials: [g*264 + m*64 + lane], lane-stride 1 -> min 2-way (free).
        float* pb = &pbuf[cur][g * 264 + lane];
        pb[0]   = accs[0];
        pb[64]  = accs[1];
        pb[128] = accs[2];
        pb[192] = accs[3];

        __syncthreads();                      // the ONLY barrier per step

        // ---- reduce (all 64 lanes): partials of waves {q,q+4,q+8,q+12} ----
        const float* pr = &pbuf[cur][q * 264 + redoff];
        float s = (pr[0] + pr[1056]) + (pr[2112] + pr[3168]);
        s += __shfl_xor(s, 16);
        s += __shfl_xor(s, 32);

        hj = fmaxf(fmaf(OMA_F, hj, ALPHA_F * (s + pcur)), 0.f);
        if (lane < 16) {
            op[0] = hj;            // fire-and-forget
            hbuf[rrow] = hj;       // wave-private publish, read next iter
        }
        op += (size_t)BATCH * HID;
        pcur = pn1; pn1 = pn2;
    }

    if (lane < 16) {
        out[(size_t)T_STEPS * BATCH * HID + (size_t)b * HID + rrow] = hj;
    }
}

// ---------------------------------------------------------------------------
// Fallback (ws too small): monolithic kernel (known-good).
// ---------------------------------------------------------------------------
__global__ __launch_bounds__(512, 2)
void ctrnn_mono(const float* __restrict__ x, const float* __restrict__ hidden,
                const float* __restrict__ noise, const float* __restrict__ W_in,
                const float* __restrict__ b_in, const float* __restrict__ W_hh,
                const float* __restrict__ b_hh, float* __restrict__ out)
{
    const int tid  = threadIdx.x;
    const int j    = tid & (HID - 1);
    const int half = tid >> 8;
    const int b    = blockIdx.x;

    __shared__ __align__(16) float hbuf[2][HID];
    __shared__ __align__(16) float xbuf[2][INSZ];
    __shared__ __align__(16) float pbuf[HID];

    float whh[128];
    const float* wrow = &W_hh[j * HID + half * 128];
#pragma unroll
    for (int k = 0; k < 128; k += 4) {
        float4 v = *reinterpret_cast<const float4*>(&wrow[k]);
        whh[k] = v.x; whh[k+1] = v.y; whh[k+2] = v.z; whh[k+3] = v.w;
    }
    float win[32];
    const float* wirow = &W_in[j * INSZ + half * 32];
#pragma unroll
    for (int k = 0; k < 32; k += 4) {
        float4 v = *reinterpret_cast<const float4*>(&wirow[k]);
        win[k] = v.x; win[k+1] = v.y; win[k+2] = v.z; win[k+3] = v.w;
    }

    float bias = 0.f, hj = 0.f, noise_j = 0.f;
    if (half == 0) {
        bias = b_in[j] + b_hh[j];
        hj = hidden[b * HID + j];
        hbuf[0][j] = hj;
        noise_j = noise[j];
        if (j < INSZ / 4) {
            *reinterpret_cast<float4*>(&xbuf[0][4 * j]) =
                *reinterpret_cast<const float4*>(&x[(size_t)b * INSZ + 4 * j]);
        }
    }
    __syncthreads();

    const int hoff = half * 128;
    const int ioff = half * 32;
    int cur = 0;
#pragma unroll 1
    for (int t = 0; t < T_STEPS; ++t) {
        float4 xnext = make_float4(0.f, 0.f, 0.f, 0.f);
        float  nnext = 0.f;
        if (half == 1) {
            if (j < INSZ / 4 && t + 1 < T_STEPS) {
                xnext = *reinterpret_cast<const float4*>(
                    &x[((size_t)(t + 1) * BATCH + b) * INSZ + 4 * j]);
            }
        } else if (t + 1 < T_STEPS) {
            nnext = noise[(t + 1) * HID + j];
        }

        float a0 = 0.f, a1 = 0.f, a2 = 0.f, a3 = 0.f;
#pragma unroll
        for (int k = 0; k < 128; k += 4) {
            float4 hv = *reinterpret_cast<const float4*>(&hbuf[cur][hoff + k]);
            a0 = fmaf(whh[k],     hv.x, a0);
            a1 = fmaf(whh[k + 1], hv.y, a1);
            a2 = fmaf(whh[k + 2], hv.z, a2);
            a3 = fmaf(whh[k + 3], hv.w, a3);
        }
#pragma unroll
        for (int k = 0; k < 32; k += 4) {
            float4 xv = *reinterpret_cast<const float4*>(&xbuf[cur][ioff + k]);
            a0 = fmaf(win[k],     xv.x, a0);
            a1 = fmaf(win[k + 1], xv.y, a1);
            a2 = fmaf(win[k + 2], xv.z, a2);
            a3 = fmaf(win[k + 3], xv.w, a3);
        }
        const float acc = (a0 + a1) + (a2 + a3);

        if (half == 1) pbuf[j] = acc;
        __syncthreads();

        const int nxt = cur ^ 1;
        if (half == 0) {
            const float pre = acc + pbuf[j] + bias + noise_j;
            hj = fmaxf(fmaf(OMA_F, hj, ALPHA_F * pre), 0.f);
            out[((size_t)t * BATCH + b) * HID + j] = hj;
            hbuf[nxt][j] = hj;
            noise_j = nnext;
        } else if (j < INSZ / 4 && t + 1 < T_STEPS) {
            *reinterpret_cast<float4*>(&xbuf[nxt][4 * j]) = xnext;
        }
        __syncthreads();
        cur = nxt;
    }

    if (half == 0) {
        out[(size_t)T_STEPS * BATCH * HID + (size_t)b * HID + j] = hj;
    }
}

extern "C" void kernel_launch(void* const* d_in, const int* in_sizes, int n_in,
                              void* d_out, int out_size, void* d_ws, size_t ws_size,
                              hipStream_t stream) {
    const float* x      = (const float*)d_in[0];
    const float* hidden = (const float*)d_in[1];
    const float* noise  = (const float*)d_in[2];
    const float* W_in   = (const float*)d_in[3];
    const float* b_in   = (const float*)d_in[4];
    const float* W_hh   = (const float*)d_in[5];
    const float* b_hh   = (const float*)d_in[6];
    float* out = (float*)d_out;

    const size_t prex_bytes = (size_t)T_STEPS * BATCH * HID * sizeof(float);
    if (ws_size >= prex_bytes) {
        float* prex = (float*)d_ws;
        hipLaunchKernelGGL(ctrnn_prex4, dim3(T_STEPS), dim3(512), 0, stream,
                           x, noise, W_in, b_in, b_hh, prex);
        hipLaunchKernelGGL(ctrnn_rec3, dim3(BATCH), dim3(1024), 0, stream,
                           hidden, prex, W_hh, out);
    } else {
        hipLaunchKernelGGL(ctrnn_mono, dim3(BATCH), dim3(512), 0, stream,
                           x, hidden, noise, W_in, b_in, W_hh, b_hh, out);
    }
}